// Round 1
// baseline (1141.778 us; speedup 1.0000x reference)
//
#include <hip/hip_runtime.h>

#define N_NODES 100000
#define N_EDGES 625000
#define HIDDEN 128
#define NUM_GRAPHS 512
#define CAP 40   // max in-degree capacity; Poisson(6.25) => P(deg>40) ~ e-43

// ---------------- embed: h[n][:] = node_emb[x[n]][:] ----------------
__global__ __launch_bounds__(256) void embed_k(const int* __restrict__ x,
                                               const float* __restrict__ emb,
                                               float* __restrict__ h) {
  int t = blockIdx.x * 256 + threadIdx.x;   // one float4 per thread
  int n = t >> 5;
  if (n >= N_NODES) return;
  int row = x[n];
  ((float4*)h)[t] = ((const float4*)(emb + (size_t)row * HIDDEN))[t & 31];
}

// ---------------- build dst-keyed adjacency (per call) ----------------
__global__ __launch_bounds__(256) void build_k(const int* __restrict__ src,
                                               const int* __restrict__ dst,
                                               int* __restrict__ cursor,
                                               int* __restrict__ slots) {
  int e = blockIdx.x * 256 + threadIdx.x;
  if (e >= N_EDGES) return;
  int d = dst[e];
  int p = atomicAdd(&cursor[d], 1);
  if (p < CAP) slots[(size_t)d * CAP + p] = src[e];
}

// ---------------- gather: t0[n] = h[n] + sum_{e: dst=n} h[src[e]] ----------------
__global__ __launch_bounds__(256) void gather_k(const float* __restrict__ h,
                                                const int* __restrict__ cursor,
                                                const int* __restrict__ slots,
                                                float* __restrict__ out) {
  int t = blockIdx.x * 256 + threadIdx.x;
  int n = t >> 5;
  if (n >= N_NODES) return;
  int c4 = t & 31;
  int deg = cursor[n];
  if (deg > CAP) deg = CAP;
  float4 acc = ((const float4*)(h + (size_t)n * HIDDEN))[c4];
  const int* sl = slots + (size_t)n * CAP;
  for (int j = 0; j < deg; j++) {
    int s = sl[j];  // broadcast across the 32 lanes of this node
    float4 v = ((const float4*)(h + (size_t)s * HIDDEN))[c4];
    acc.x += v.x; acc.y += v.y; acc.z += v.z; acc.w += v.w;
  }
  ((float4*)out)[t] = acc;
}

// ---------------- node GEMM: out = [relu](A @ W + b), W is 128x128 ----------------
// 64 rows/block, 256 threads: thread tile = 8 rows x 4 cols.
// W staged in LDS (64KB). A read from global (each element fetched once,
// 32 same-rg lanes broadcast). __syncthreads before store => in-place safe.
template <bool RELU>
__global__ __launch_bounds__(256) void gemm_k(const float* __restrict__ A,
                                              const float* __restrict__ W,
                                              const float* __restrict__ bias,
                                              float* __restrict__ out) {
  __shared__ float Ws[HIDDEN * HIDDEN];   // 64 KB
  int tid = threadIdx.x;
  int row0 = blockIdx.x * 64;

  {
    const float4* W4 = (const float4*)W;
    float4* Ws4 = (float4*)Ws;
#pragma unroll
    for (int i = 0; i < 16; i++) Ws4[tid + 256 * i] = W4[tid + 256 * i];
  }
  __syncthreads();

  int cg = tid & 31;        // 32 col-groups of 4 cols
  int rg = tid >> 5;        // 8 row-groups of 8 rows
  const float4* Ar[8];
#pragma unroll
  for (int i = 0; i < 8; i++) {
    int r = row0 + rg * 8 + i;
    if (r > N_NODES - 1) r = N_NODES - 1;   // clamp; OOB rows never stored
    Ar[i] = (const float4*)(A + (size_t)r * HIDDEN);
  }

  float acc[8][4];
#pragma unroll
  for (int i = 0; i < 8; i++)
#pragma unroll
    for (int j = 0; j < 4; j++) acc[i][j] = 0.f;

  for (int kq = 0; kq < 32; kq++) {
    int k = kq * 4;
    float4 w0 = *(const float4*)&Ws[(k + 0) * HIDDEN + cg * 4];
    float4 w1 = *(const float4*)&Ws[(k + 1) * HIDDEN + cg * 4];
    float4 w2 = *(const float4*)&Ws[(k + 2) * HIDDEN + cg * 4];
    float4 w3 = *(const float4*)&Ws[(k + 3) * HIDDEN + cg * 4];
#pragma unroll
    for (int i = 0; i < 8; i++) {
      float4 a = Ar[i][kq];
      acc[i][0] = fmaf(a.x, w0.x, fmaf(a.y, w1.x, fmaf(a.z, w2.x, fmaf(a.w, w3.x, acc[i][0]))));
      acc[i][1] = fmaf(a.x, w0.y, fmaf(a.y, w1.y, fmaf(a.z, w2.y, fmaf(a.w, w3.y, acc[i][1]))));
      acc[i][2] = fmaf(a.x, w0.z, fmaf(a.y, w1.z, fmaf(a.z, w2.z, fmaf(a.w, w3.z, acc[i][2]))));
      acc[i][3] = fmaf(a.x, w0.w, fmaf(a.y, w1.w, fmaf(a.z, w2.w, fmaf(a.w, w3.w, acc[i][3]))));
    }
  }

  __syncthreads();  // all A reads done before any store => in-place (out==A) safe

  float4 bv = ((const float4*)bias)[cg];
#pragma unroll
  for (int i = 0; i < 8; i++) {
    int row = row0 + rg * 8 + i;
    if (row < N_NODES) {
      float4 o;
      o.x = acc[i][0] + bv.x;
      o.y = acc[i][1] + bv.y;
      o.z = acc[i][2] + bv.z;
      o.w = acc[i][3] + bv.w;
      if (RELU) {
        o.x = fmaxf(o.x, 0.f); o.y = fmaxf(o.y, 0.f);
        o.z = fmaxf(o.z, 0.f); o.w = fmaxf(o.w, 0.f);
      }
      ((float4*)(out + (size_t)row * HIDDEN))[cg] = o;
    }
  }
}

// ---------------- pool: g[batch[n]] += h[n] ----------------
__global__ __launch_bounds__(256) void pool_k(const float* __restrict__ h,
                                              const int* __restrict__ batch,
                                              float* __restrict__ g) {
  int t = blockIdx.x * 256 + threadIdx.x;
  int n = t >> 5;
  if (n >= N_NODES) return;
  int b = batch[n];
  float4 v = ((const float4*)h)[t];
  float* dp = g + (size_t)b * HIDDEN + (size_t)(t & 31) * 4;
  unsafeAtomicAdd(dp + 0, v.x);
  unsafeAtomicAdd(dp + 1, v.y);
  unsafeAtomicAdd(dp + 2, v.z);
  unsafeAtomicAdd(dp + 3, v.w);
}

// ---------------- final MLP: 128 -> 64 -> 32 -> 1, one block per graph ----------------
__global__ __launch_bounds__(64) void mlp_k(const float* __restrict__ g,
                                            const float* __restrict__ W1, const float* __restrict__ b1,
                                            const float* __restrict__ W2, const float* __restrict__ b2,
                                            const float* __restrict__ W3, const float* __restrict__ b3,
                                            float* __restrict__ out) {
  __shared__ float r1[128];
  __shared__ float r2[64];
  __shared__ float r3[32];
  int gi = blockIdx.x, t = threadIdx.x;
  r1[t] = g[(size_t)gi * 128 + t];
  r1[t + 64] = g[(size_t)gi * 128 + 64 + t];
  __syncthreads();
  float s = b1[t];
  for (int k = 0; k < 128; k++) s = fmaf(r1[k], W1[k * 64 + t], s);
  r2[t] = fmaxf(s, 0.f);
  __syncthreads();
  if (t < 32) {
    float s2 = b2[t];
    for (int k = 0; k < 64; k++) s2 = fmaf(r2[k], W2[k * 32 + t], s2);
    r3[t] = fmaxf(s2, 0.f);
  }
  __syncthreads();
  float pv = (t < 32) ? r3[t] * W3[t] : 0.f;
#pragma unroll
  for (int off = 32; off > 0; off >>= 1) pv += __shfl_down(pv, off);
  if (t == 0) out[gi] = pv + b3[0];
}

extern "C" void kernel_launch(void* const* d_in, const int* in_sizes, int n_in,
                              void* d_out, int out_size, void* d_ws, size_t ws_size,
                              hipStream_t stream) {
  const int* x = (const int*)d_in[0];
  const int* src = (const int*)d_in[1];
  const int* dst = src + N_EDGES;
  // d_in[2] = edge_attr, d_in[5] = edge_emb: computed-but-unused in reference
  const int* batch = (const int*)d_in[3];
  const float* node_emb = (const float*)d_in[4];
  const float* cW1 = (const float*)d_in[6];
  const float* cb1 = (const float*)d_in[7];
  const float* cW2 = (const float*)d_in[8];
  const float* cb2 = (const float*)d_in[9];
  const float* mW1 = (const float*)d_in[10];
  const float* mb1 = (const float*)d_in[11];
  const float* mW2 = (const float*)d_in[12];
  const float* mb2 = (const float*)d_in[13];
  const float* mW3 = (const float*)d_in[14];
  const float* mb3 = (const float*)d_in[15];
  float* out = (float*)d_out;

  char* p = (char*)d_ws;
  const size_t HB = (size_t)N_NODES * HIDDEN * sizeof(float);  // 51.2 MB
  float* h = (float*)p;        p += HB;
  float* t0 = (float*)p;       p += HB;
  int* cursor = (int*)p;       p += (size_t)N_NODES * sizeof(int);
  int* slots = (int*)p;        p += (size_t)N_NODES * CAP * sizeof(int);
  float* g = (float*)p;        p += (size_t)NUM_GRAPHS * HIDDEN * sizeof(float);

  hipMemsetAsync(cursor, 0, (size_t)N_NODES * sizeof(int), stream);
  embed_k<<<(N_NODES * 32 + 255) / 256, 256, 0, stream>>>(x, node_emb, h);
  build_k<<<(N_EDGES + 255) / 256, 256, 0, stream>>>(src, dst, cursor, slots);

  const int gemm_grid = (N_NODES + 63) / 64;  // 1563
  for (int l = 0; l < 4; l++) {
    gather_k<<<(N_NODES * 32 + 255) / 256, 256, 0, stream>>>(h, cursor, slots, t0);
    gemm_k<true><<<gemm_grid, 256, 0, stream>>>(t0, cW1 + (size_t)l * HIDDEN * HIDDEN,
                                                cb1 + (size_t)l * HIDDEN, t0);
    gemm_k<false><<<gemm_grid, 256, 0, stream>>>(t0, cW2 + (size_t)l * HIDDEN * HIDDEN,
                                                 cb2 + (size_t)l * HIDDEN, h);
  }

  hipMemsetAsync(g, 0, (size_t)NUM_GRAPHS * HIDDEN * sizeof(float), stream);
  pool_k<<<(N_NODES * 32 + 255) / 256, 256, 0, stream>>>(h, batch, g);
  mlp_k<<<NUM_GRAPHS, 64, 0, stream>>>(g, mW1, mb1, mW2, mb2, mW3, mb3, out);
}

// Round 2
// 939.016 us; speedup vs baseline: 1.2159x; 1.2159x over previous
//
#include <hip/hip_runtime.h>

#define N_NODES 100000
#define N_EDGES 625000
#define HIDDEN 128
#define NUM_GRAPHS 512
#define CAP 40   // max in-degree capacity; Poisson(6.25) => P(deg>40) ~ e-43

// ---------------- embed: h[n][:] = node_emb[x[n]][:] ----------------
__global__ __launch_bounds__(256) void embed_k(const int* __restrict__ x,
                                               const float* __restrict__ emb,
                                               float* __restrict__ h) {
  int t = blockIdx.x * 256 + threadIdx.x;   // one float4 per thread
  int n = t >> 5;
  if (n >= N_NODES) return;
  int row = x[n];
  ((float4*)h)[t] = ((const float4*)(emb + (size_t)row * HIDDEN))[t & 31];
}

// ---------------- build dst-keyed adjacency (per call) ----------------
__global__ __launch_bounds__(256) void build_k(const int* __restrict__ src,
                                               const int* __restrict__ dst,
                                               int* __restrict__ cursor,
                                               int* __restrict__ slots) {
  int e = blockIdx.x * 256 + threadIdx.x;
  if (e >= N_EDGES) return;
  int d = dst[e];
  int p = atomicAdd(&cursor[d], 1);
  if (p < CAP) slots[(size_t)d * CAP + p] = src[e];
}

// ---------------- gather: t0[n] = h[n] + sum_{e: dst=n} h[src[e]] ----------------
__global__ __launch_bounds__(256) void gather_k(const float* __restrict__ h,
                                                const int* __restrict__ cursor,
                                                const int* __restrict__ slots,
                                                float* __restrict__ out) {
  int t = blockIdx.x * 256 + threadIdx.x;
  int n = t >> 5;
  if (n >= N_NODES) return;
  int c4 = t & 31;
  int deg = cursor[n];
  if (deg > CAP) deg = CAP;
  float4 acc = ((const float4*)(h + (size_t)n * HIDDEN))[c4];
  const int* sl = slots + (size_t)n * CAP;
  for (int j = 0; j < deg; j++) {
    int s = sl[j];  // broadcast across the 32 lanes of this node
    float4 v = ((const float4*)(h + (size_t)s * HIDDEN))[c4];
    acc.x += v.x; acc.y += v.y; acc.z += v.z; acc.w += v.w;
  }
  ((float4*)out)[t] = acc;
}

// ---------------- node GEMM: out = [relu](A @ W + b), W is 128x128 ----------------
// 64 rows/block, 256 threads: thread tile = 8 rows x 4 cols.
// W staged in LDS (64KB). A read from global (each element fetched once,
// 32 same-rg lanes broadcast). __syncthreads before store => in-place safe.
template <bool RELU>
__global__ __launch_bounds__(256) void gemm_k(const float* __restrict__ A,
                                              const float* __restrict__ W,
                                              const float* __restrict__ bias,
                                              float* __restrict__ out) {
  __shared__ float Ws[HIDDEN * HIDDEN];   // 64 KB
  int tid = threadIdx.x;
  int row0 = blockIdx.x * 64;

  {
    const float4* W4 = (const float4*)W;
    float4* Ws4 = (float4*)Ws;
#pragma unroll
    for (int i = 0; i < 16; i++) Ws4[tid + 256 * i] = W4[tid + 256 * i];
  }
  __syncthreads();

  int cg = tid & 31;        // 32 col-groups of 4 cols
  int rg = tid >> 5;        // 8 row-groups of 8 rows
  const float4* Ar[8];
#pragma unroll
  for (int i = 0; i < 8; i++) {
    int r = row0 + rg * 8 + i;
    if (r > N_NODES - 1) r = N_NODES - 1;   // clamp; OOB rows never stored
    Ar[i] = (const float4*)(A + (size_t)r * HIDDEN);
  }

  float acc[8][4];
#pragma unroll
  for (int i = 0; i < 8; i++)
#pragma unroll
    for (int j = 0; j < 4; j++) acc[i][j] = 0.f;

  for (int kq = 0; kq < 32; kq++) {
    int k = kq * 4;
    float4 w0 = *(const float4*)&Ws[(k + 0) * HIDDEN + cg * 4];
    float4 w1 = *(const float4*)&Ws[(k + 1) * HIDDEN + cg * 4];
    float4 w2 = *(const float4*)&Ws[(k + 2) * HIDDEN + cg * 4];
    float4 w3 = *(const float4*)&Ws[(k + 3) * HIDDEN + cg * 4];
#pragma unroll
    for (int i = 0; i < 8; i++) {
      float4 a = Ar[i][kq];
      acc[i][0] = fmaf(a.x, w0.x, fmaf(a.y, w1.x, fmaf(a.z, w2.x, fmaf(a.w, w3.x, acc[i][0]))));
      acc[i][1] = fmaf(a.x, w0.y, fmaf(a.y, w1.y, fmaf(a.z, w2.y, fmaf(a.w, w3.y, acc[i][1]))));
      acc[i][2] = fmaf(a.x, w0.z, fmaf(a.y, w1.z, fmaf(a.z, w2.z, fmaf(a.w, w3.z, acc[i][2]))));
      acc[i][3] = fmaf(a.x, w0.w, fmaf(a.y, w1.w, fmaf(a.z, w2.w, fmaf(a.w, w3.w, acc[i][3]))));
    }
  }

  __syncthreads();  // all A reads done before any store => in-place (out==A) safe

  float4 bv = ((const float4*)bias)[cg];
#pragma unroll
  for (int i = 0; i < 8; i++) {
    int row = row0 + rg * 8 + i;
    if (row < N_NODES) {
      float4 o;
      o.x = acc[i][0] + bv.x;
      o.y = acc[i][1] + bv.y;
      o.z = acc[i][2] + bv.z;
      o.w = acc[i][3] + bv.w;
      if (RELU) {
        o.x = fmaxf(o.x, 0.f); o.y = fmaxf(o.y, 0.f);
        o.z = fmaxf(o.z, 0.f); o.w = fmaxf(o.w, 0.f);
      }
      ((float4*)(out + (size_t)row * HIDDEN))[cg] = o;
    }
  }
}

// ---------------- pool (segmented, batch is SORTED => no atomics) ----------------
// One block per graph: binary-search [start,end) in batch, coalesced strided
// row sum (8 rowgroups x 32 colgroups of float4), LDS reduce across rowgroups.
__global__ __launch_bounds__(256) void pool_seg_k(const float* __restrict__ h,
                                                  const int* __restrict__ batch,
                                                  float* __restrict__ g) {
  __shared__ int se[2];
  __shared__ float4 red[8][32];
  int gi = blockIdx.x;
  int tid = threadIdx.x;
  if (tid < 2) {
    int target = gi + tid;            // lower_bound(batch, target)
    int lo = 0, hi = N_NODES;
    while (lo < hi) {
      int mid = (lo + hi) >> 1;
      if (batch[mid] < target) lo = mid + 1; else hi = mid;
    }
    se[tid] = lo;
  }
  __syncthreads();
  int start = se[0], end = se[1];
  int cg = tid & 31, rg = tid >> 5;
  float4 acc = {0.f, 0.f, 0.f, 0.f};
  for (int r = start + rg; r < end; r += 8) {
    float4 v = ((const float4*)(h + (size_t)r * HIDDEN))[cg];
    acc.x += v.x; acc.y += v.y; acc.z += v.z; acc.w += v.w;
  }
  red[rg][cg] = acc;
  __syncthreads();
  if (rg == 0) {
    float4 s = red[0][cg];
#pragma unroll
    for (int i = 1; i < 8; i++) {
      float4 v = red[i][cg];
      s.x += v.x; s.y += v.y; s.z += v.z; s.w += v.w;
    }
    ((float4*)(g + (size_t)gi * HIDDEN))[cg] = s;
  }
}

// ---------------- final MLP: 128 -> 64 -> 32 -> 1, one block per graph ----------------
__global__ __launch_bounds__(64) void mlp_k(const float* __restrict__ g,
                                            const float* __restrict__ W1, const float* __restrict__ b1,
                                            const float* __restrict__ W2, const float* __restrict__ b2,
                                            const float* __restrict__ W3, const float* __restrict__ b3,
                                            float* __restrict__ out) {
  __shared__ float r1[128];
  __shared__ float r2[64];
  __shared__ float r3[32];
  int gi = blockIdx.x, t = threadIdx.x;
  r1[t] = g[(size_t)gi * 128 + t];
  r1[t + 64] = g[(size_t)gi * 128 + 64 + t];
  __syncthreads();
  float s = b1[t];
  for (int k = 0; k < 128; k++) s = fmaf(r1[k], W1[k * 64 + t], s);
  r2[t] = fmaxf(s, 0.f);
  __syncthreads();
  if (t < 32) {
    float s2 = b2[t];
    for (int k = 0; k < 64; k++) s2 = fmaf(r2[k], W2[k * 32 + t], s2);
    r3[t] = fmaxf(s2, 0.f);
  }
  __syncthreads();
  float pv = (t < 32) ? r3[t] * W3[t] : 0.f;
#pragma unroll
  for (int off = 32; off > 0; off >>= 1) pv += __shfl_down(pv, off);
  if (t == 0) out[gi] = pv + b3[0];
}

extern "C" void kernel_launch(void* const* d_in, const int* in_sizes, int n_in,
                              void* d_out, int out_size, void* d_ws, size_t ws_size,
                              hipStream_t stream) {
  const int* x = (const int*)d_in[0];
  const int* src = (const int*)d_in[1];
  const int* dst = src + N_EDGES;
  // d_in[2] = edge_attr, d_in[5] = edge_emb: computed-but-unused in reference
  const int* batch = (const int*)d_in[3];
  const float* node_emb = (const float*)d_in[4];
  const float* cW1 = (const float*)d_in[6];
  const float* cb1 = (const float*)d_in[7];
  const float* cW2 = (const float*)d_in[8];
  const float* cb2 = (const float*)d_in[9];
  const float* mW1 = (const float*)d_in[10];
  const float* mb1 = (const float*)d_in[11];
  const float* mW2 = (const float*)d_in[12];
  const float* mb2 = (const float*)d_in[13];
  const float* mW3 = (const float*)d_in[14];
  const float* mb3 = (const float*)d_in[15];
  float* out = (float*)d_out;

  char* p = (char*)d_ws;
  const size_t HB = (size_t)N_NODES * HIDDEN * sizeof(float);  // 51.2 MB
  float* h = (float*)p;        p += HB;
  float* t0 = (float*)p;       p += HB;
  int* cursor = (int*)p;       p += (size_t)N_NODES * sizeof(int);
  int* slots = (int*)p;        p += (size_t)N_NODES * CAP * sizeof(int);
  float* g = (float*)p;        p += (size_t)NUM_GRAPHS * HIDDEN * sizeof(float);

  hipMemsetAsync(cursor, 0, (size_t)N_NODES * sizeof(int), stream);
  embed_k<<<(N_NODES * 32 + 255) / 256, 256, 0, stream>>>(x, node_emb, h);
  build_k<<<(N_EDGES + 255) / 256, 256, 0, stream>>>(src, dst, cursor, slots);

  const int gemm_grid = (N_NODES + 63) / 64;  // 1563
  for (int l = 0; l < 4; l++) {
    gather_k<<<(N_NODES * 32 + 255) / 256, 256, 0, stream>>>(h, cursor, slots, t0);
    gemm_k<true><<<gemm_grid, 256, 0, stream>>>(t0, cW1 + (size_t)l * HIDDEN * HIDDEN,
                                                cb1 + (size_t)l * HIDDEN, t0);
    gemm_k<false><<<gemm_grid, 256, 0, stream>>>(t0, cW2 + (size_t)l * HIDDEN * HIDDEN,
                                                 cb2 + (size_t)l * HIDDEN, h);
  }

  pool_seg_k<<<NUM_GRAPHS, 256, 0, stream>>>(h, batch, g);
  mlp_k<<<NUM_GRAPHS, 64, 0, stream>>>(g, mW1, mb1, mW2, mb2, mW3, mb3, out);
}

// Round 3
// 526.554 us; speedup vs baseline: 2.1684x; 1.7833x over previous
//
#include <hip/hip_runtime.h>

#define N_NODES 100000
#define N_EDGES 625000
#define HIDDEN 128
#define NUM_GRAPHS 512
#define CAP 40   // max in-degree capacity; Poisson(6.25) => P(deg>40) ~ e-43

typedef unsigned int uint;
typedef unsigned short ushort;
typedef short v8s __attribute__((ext_vector_type(8)));
typedef float v16f __attribute__((ext_vector_type(16)));

__device__ __forceinline__ float b2f_lo(uint u) { return __uint_as_float(u << 16); }
__device__ __forceinline__ float b2f_hi(uint u) { return __uint_as_float(u & 0xffff0000u); }
__device__ __forceinline__ uint f2b(float f) {  // RNE f32 -> bf16 bits
  uint u = __float_as_uint(f);
  return (u + 0x7fffu + ((u >> 16) & 1u)) >> 16;
}

// ---------------- weight transpose+quantize: Wt[mat][n][k] bf16 ----------------
__global__ __launch_bounds__(256) void wtrans_k(const float* __restrict__ W1,
                                                const float* __restrict__ W2,
                                                ushort* __restrict__ Wt) {
  int mat = blockIdx.x;                       // 0..7 = layer*2 + which
  const float* W = ((mat & 1) ? W2 : W1) + (size_t)(mat >> 1) * 16384;
  ushort* o = Wt + (size_t)mat * 16384;
#pragma unroll
  for (int j = 0; j < 64; j++) {
    int idx = threadIdx.x + 256 * j;          // coalesced read W[k][n]
    int k = idx >> 7, n = idx & 127;
    o[n * 128 + k] = (ushort)f2b(W[idx]);
  }
}

// ---------------- embed: h[n][:] = bf16(node_emb[x[n]][:]) ----------------
__global__ __launch_bounds__(256) void embed_k(const int* __restrict__ x,
                                               const float* __restrict__ emb,
                                               ushort* __restrict__ h) {
  int t = blockIdx.x * 256 + threadIdx.x;     // one 8-col chunk per thread
  int n = t >> 4;
  if (n >= N_NODES) return;
  int c = t & 15;
  const float4* e = (const float4*)(emb + (size_t)x[n] * HIDDEN + c * 8);
  float4 a = e[0], b = e[1];
  uint4 o;
  o.x = f2b(a.x) | (f2b(a.y) << 16);
  o.y = f2b(a.z) | (f2b(a.w) << 16);
  o.z = f2b(b.x) | (f2b(b.y) << 16);
  o.w = f2b(b.z) | (f2b(b.w) << 16);
  ((uint4*)h)[t] = o;
}

// ---------------- build dst-keyed adjacency (per call) ----------------
__global__ __launch_bounds__(256) void build_k(const int* __restrict__ src,
                                               const int* __restrict__ dst,
                                               int* __restrict__ cursor,
                                               int* __restrict__ slots) {
  int e = blockIdx.x * 256 + threadIdx.x;
  if (e >= N_EDGES) return;
  int d = dst[e];
  int p = atomicAdd(&cursor[d], 1);
  if (p < CAP) slots[(size_t)d * CAP + p] = src[e];
}

// ---------------- gather: t0[n] = bf16( h[n] + sum_{e: dst=n} h[src[e]] ) ----------------
__global__ __launch_bounds__(256) void gather_k(const ushort* __restrict__ h,
                                                const int* __restrict__ cursor,
                                                const int* __restrict__ slots,
                                                ushort* __restrict__ out) {
  int t = blockIdx.x * 256 + threadIdx.x;
  int n = t >> 4;
  if (n >= N_NODES) return;
  int c = t & 15;
  const uint4* H = (const uint4*)h;           // 16 uint4 per 128-col row
  uint4 v = H[n * 16 + c];
  float acc[8];
  acc[0] = b2f_lo(v.x); acc[1] = b2f_hi(v.x);
  acc[2] = b2f_lo(v.y); acc[3] = b2f_hi(v.y);
  acc[4] = b2f_lo(v.z); acc[5] = b2f_hi(v.z);
  acc[6] = b2f_lo(v.w); acc[7] = b2f_hi(v.w);
  int deg = cursor[n];
  if (deg > CAP) deg = CAP;
  const int* sl = slots + (size_t)n * CAP;
  for (int j = 0; j < deg; j++) {
    int s = sl[j];                            // broadcast across the 16 lanes of this node
    uint4 w = H[s * 16 + c];
    acc[0] += b2f_lo(w.x); acc[1] += b2f_hi(w.x);
    acc[2] += b2f_lo(w.y); acc[3] += b2f_hi(w.y);
    acc[4] += b2f_lo(w.z); acc[5] += b2f_hi(w.z);
    acc[6] += b2f_lo(w.w); acc[7] += b2f_hi(w.w);
  }
  uint4 o;
  o.x = f2b(acc[0]) | (f2b(acc[1]) << 16);
  o.y = f2b(acc[2]) | (f2b(acc[3]) << 16);
  o.z = f2b(acc[4]) | (f2b(acc[5]) << 16);
  o.w = f2b(acc[6]) | (f2b(acc[7]) << 16);
  ((uint4*)out)[t] = o;
}

// ---------------- MFMA GEMM: out = [relu](A @ W + b), bf16 in/out, f32 acc ----------------
// Block = 256 thr = 4 waves, 128 rows/block (32/wave). Entire Wt (bf16 [n][k])
// lives in VGPRs as B-fragments (128 VGPRs), loaded once per wave (L2-cached).
// A streamed from global as dwordx4 fragments. In-place safe: each wave reads
// and writes only its own 32 rows, and all K-loop loads complete before stores.
template <bool RELU>
__global__ __launch_bounds__(256, 2) void gemm_bf16_k(const ushort* __restrict__ A,
                                                      const ushort* __restrict__ Wt,
                                                      const float* __restrict__ bias,
                                                      ushort* __restrict__ out) {
  int tid = threadIdx.x;
  int lane = tid & 63;
  int w = tid >> 6;
  int l31 = lane & 31;
  int khalf = lane >> 5;                      // 0/1: which 8-wide k half
  int row = blockIdx.x * 128 + w * 32 + l31;
  int arow = row < N_NODES ? row : N_NODES - 1;  // clamp; OOB rows never stored

  union U { uint4 u; v8s s; };
  U B[4][8];                                  // [coltile][kstep] -> 128 VGPRs
#pragma unroll
  for (int c = 0; c < 4; c++)
#pragma unroll
    for (int ks = 0; ks < 8; ks++)
      B[c][ks].u = *(const uint4*)(Wt + ((c * 32 + l31) << 7) + ks * 16 + khalf * 8);

  float bv[4];
#pragma unroll
  for (int c = 0; c < 4; c++) bv[c] = bias[c * 32 + l31];

  v16f acc[4] = {};

  const ushort* Ab = A + (size_t)arow * HIDDEN + khalf * 8;
#pragma unroll
  for (int ks = 0; ks < 8; ks++) {
    U a;
    a.u = *(const uint4*)(Ab + ks * 16);
#pragma unroll
    for (int c = 0; c < 4; c++)
      acc[c] = __builtin_amdgcn_mfma_f32_32x32x16_bf16(a.s, B[c][ks].s, acc[c], 0, 0, 0);
  }

  // C/D layout (measured m74/m101): col = lane&31, row = (reg&3)+8*(reg>>2)+4*(lane>>5)
  int rbase = blockIdx.x * 128 + w * 32 + 4 * khalf;
#pragma unroll
  for (int c = 0; c < 4; c++) {
    int col = c * 32 + l31;
#pragma unroll
    for (int r = 0; r < 16; r++) {
      int orow = rbase + (r & 3) + 8 * (r >> 2);
      if (orow < N_NODES) {
        float vv = acc[c][r] + bv[c];
        if (RELU) vv = fmaxf(vv, 0.f);
        out[(size_t)orow * HIDDEN + col] = (ushort)f2b(vv);
      }
    }
  }
}

// ---------------- pool (segmented, batch SORTED => no atomics), bf16 in, f32 out ----------------
__global__ __launch_bounds__(256) void pool_seg_k(const ushort* __restrict__ h,
                                                  const int* __restrict__ batch,
                                                  float* __restrict__ g) {
  __shared__ int se[2];
  __shared__ float red[16][16][8];
  int gi = blockIdx.x;
  int tid = threadIdx.x;
  if (tid < 2) {
    int target = gi + tid;                    // lower_bound(batch, target)
    int lo = 0, hi = N_NODES;
    while (lo < hi) {
      int mid = (lo + hi) >> 1;
      if (batch[mid] < target) lo = mid + 1; else hi = mid;
    }
    se[tid] = lo;
  }
  __syncthreads();
  int start = se[0], end = se[1];
  int cg = tid & 15, rg = tid >> 4;
  float acc[8] = {0.f, 0.f, 0.f, 0.f, 0.f, 0.f, 0.f, 0.f};
  for (int r = start + rg; r < end; r += 16) {
    uint4 v = ((const uint4*)h)[r * 16 + cg];
    acc[0] += b2f_lo(v.x); acc[1] += b2f_hi(v.x);
    acc[2] += b2f_lo(v.y); acc[3] += b2f_hi(v.y);
    acc[4] += b2f_lo(v.z); acc[5] += b2f_hi(v.z);
    acc[6] += b2f_lo(v.w); acc[7] += b2f_hi(v.w);
  }
#pragma unroll
  for (int j = 0; j < 8; j++) red[rg][cg][j] = acc[j];
  __syncthreads();
  if (rg == 0) {
    float s[8];
#pragma unroll
    for (int j = 0; j < 8; j++) s[j] = red[0][cg][j];
#pragma unroll
    for (int i = 1; i < 16; i++)
#pragma unroll
      for (int j = 0; j < 8; j++) s[j] += red[i][cg][j];
    float4* gp = (float4*)(g + (size_t)gi * HIDDEN + cg * 8);
    gp[0] = make_float4(s[0], s[1], s[2], s[3]);
    gp[1] = make_float4(s[4], s[5], s[6], s[7]);
  }
}

// ---------------- final MLP: 128 -> 64 -> 32 -> 1, one block per graph ----------------
__global__ __launch_bounds__(64) void mlp_k(const float* __restrict__ g,
                                            const float* __restrict__ W1, const float* __restrict__ b1,
                                            const float* __restrict__ W2, const float* __restrict__ b2,
                                            const float* __restrict__ W3, const float* __restrict__ b3,
                                            float* __restrict__ out) {
  __shared__ float r1[128];
  __shared__ float r2[64];
  __shared__ float r3[32];
  int gi = blockIdx.x, t = threadIdx.x;
  r1[t] = g[(size_t)gi * 128 + t];
  r1[t + 64] = g[(size_t)gi * 128 + 64 + t];
  __syncthreads();
  float s = b1[t];
  for (int k = 0; k < 128; k++) s = fmaf(r1[k], W1[k * 64 + t], s);
  r2[t] = fmaxf(s, 0.f);
  __syncthreads();
  if (t < 32) {
    float s2 = b2[t];
    for (int k = 0; k < 64; k++) s2 = fmaf(r2[k], W2[k * 32 + t], s2);
    r3[t] = fmaxf(s2, 0.f);
  }
  __syncthreads();
  float pv = (t < 32) ? r3[t] * W3[t] : 0.f;
#pragma unroll
  for (int off = 32; off > 0; off >>= 1) pv += __shfl_down(pv, off);
  if (t == 0) out[gi] = pv + b3[0];
}

extern "C" void kernel_launch(void* const* d_in, const int* in_sizes, int n_in,
                              void* d_out, int out_size, void* d_ws, size_t ws_size,
                              hipStream_t stream) {
  const int* x = (const int*)d_in[0];
  const int* src = (const int*)d_in[1];
  const int* dst = src + N_EDGES;
  // d_in[2] = edge_attr, d_in[5] = edge_emb: computed-but-unused in reference
  const int* batch = (const int*)d_in[3];
  const float* node_emb = (const float*)d_in[4];
  const float* cW1 = (const float*)d_in[6];
  const float* cb1 = (const float*)d_in[7];
  const float* cW2 = (const float*)d_in[8];
  const float* cb2 = (const float*)d_in[9];
  const float* mW1 = (const float*)d_in[10];
  const float* mb1 = (const float*)d_in[11];
  const float* mW2 = (const float*)d_in[12];
  const float* mb2 = (const float*)d_in[13];
  const float* mW3 = (const float*)d_in[14];
  const float* mb3 = (const float*)d_in[15];
  float* out = (float*)d_out;

  char* p = (char*)d_ws;
  const size_t HB = (size_t)N_NODES * HIDDEN * sizeof(ushort);  // 25.6 MB
  ushort* h = (ushort*)p;      p += HB;
  ushort* t0 = (ushort*)p;     p += HB;
  ushort* Wtb = (ushort*)p;    p += (size_t)8 * 16384 * sizeof(ushort);
  int* cursor = (int*)p;       p += (size_t)N_NODES * sizeof(int);
  int* slots = (int*)p;        p += (size_t)N_NODES * CAP * sizeof(int);
  float* g = (float*)p;        p += (size_t)NUM_GRAPHS * HIDDEN * sizeof(float);

  hipMemsetAsync(cursor, 0, (size_t)N_NODES * sizeof(int), stream);
  wtrans_k<<<8, 256, 0, stream>>>(cW1, cW2, Wtb);
  embed_k<<<(N_NODES * 16 + 255) / 256, 256, 0, stream>>>(x, node_emb, h);
  build_k<<<(N_EDGES + 255) / 256, 256, 0, stream>>>(src, dst, cursor, slots);

  const int gemm_grid = (N_NODES + 127) / 128;  // 782
  for (int l = 0; l < 4; l++) {
    gather_k<<<(N_NODES * 16 + 255) / 256, 256, 0, stream>>>(h, cursor, slots, t0);
    gemm_bf16_k<true><<<gemm_grid, 256, 0, stream>>>(t0, Wtb + (size_t)(2 * l) * 16384,
                                                     cb1 + (size_t)l * HIDDEN, t0);
    gemm_bf16_k<false><<<gemm_grid, 256, 0, stream>>>(t0, Wtb + (size_t)(2 * l + 1) * 16384,
                                                      cb2 + (size_t)l * HIDDEN, h);
  }

  pool_seg_k<<<NUM_GRAPHS, 256, 0, stream>>>(h, batch, g);
  mlp_k<<<NUM_GRAPHS, 64, 0, stream>>>(g, mW1, mb1, mW2, mb2, mW3, mb3, out);
}